// Round 2
// baseline (28.676 us; speedup 1.0000x reference)
//
#include <hip/hip_runtime.h>

#define YDIM 30
#define PLANE4 16384            // 256*256/4 float4 per (y) plane
#define NTHR 256
#define NBLK 512                // 512 blocks * 256 thr * 4 pix = 524288 pixels

__global__ __launch_bounds__(NTHR) void drl_main(const float4* __restrict__ out,
                                                 float* __restrict__ partial) {
    const int g = blockIdx.x * NTHR + threadIdx.x;     // float4-group id, 0..131071
    const int b = g >> 14;                             // batch (16384 groups/batch)
    const int hw4 = g & 16383;

    const float4* p0 = out + (size_t)b * (2 * YDIM * PLANE4) + hw4;  // out[b][0][y][...]
    const float4* p1 = p0 + YDIM * PLANE4;                            // out[b][1][y][...]

    // streaming argmin-with-snapshot scan over out0 (no c0[] array needed)
    float run_s [4] = {0.f,0.f,0.f,0.f};   // prefix  sum c0[j], j<=y
    float run_sx[4] = {0.f,0.f,0.f,0.f};   // prefix  sum j*c0[j]
    float snap_s [4] = {0.f,0.f,0.f,0.f};  // prefix sums captured at j<d
    float snap_sx[4] = {0.f,0.f,0.f,0.f};
    float best[4] = {-7.f,-7.f,-7.f,-7.f}; // diff[0] = -DIST_IND
    float fd  [4] = {0.f,0.f,0.f,0.f};     // argmin index d (as float)
    float prev[4];

#pragma unroll
    for (int y = 0; y < YDIM; ++y) {
        float4 v = p0[y * PLANE4];
        float cur[4] = {v.x, v.y, v.z, v.w};
        if (y >= 2 && y <= YDIM - 2) {     // diff[1] and diff[YDIM-1] forced to 0 in ref
#pragma unroll
            for (int c = 0; c < 4; ++c) {
                float df = cur[c] - prev[c];
                bool lt = df < best[c];    // strict < == first-occurrence argmin
                best[c]    = lt ? df         : best[c];
                fd[c]      = lt ? (float)y   : fd[c];
                snap_s[c]  = lt ? run_s[c]   : snap_s[c];   // sums over j < y
                snap_sx[c] = lt ? run_sx[c]  : snap_sx[c];
            }
        }
#pragma unroll
        for (int c = 0; c < 4; ++c) {
            run_s[c]  += cur[c];
            run_sx[c]  = fmaf((float)y, cur[c], run_sx[c]);
            prev[c]    = cur[c];
        }
    }

    // per-pixel OLS fit parameters (reference quirks preserved)
    float sc_b[4], itc_b[4], sc_a[4], itc_a[4];
#pragma unroll
    for (int c = 0; c < 4; ++c) {
        float nb  = fd[c];                    // segment-before length = d
        float na  = (float)YDIM - nb;         // >= 2 always (d <= 28)
        float nsb = fmaxf(nb, 1.f);
        float sy_b  = snap_s[c];
        float sxy_b = snap_sx[c];
        float sy_a  = run_s[c]  - sy_b;
        float sxy_a = (run_sx[c] - snap_sx[c]) - nb * sy_a;  // sum (y-d)*c0[y], y>=d
        float mxb = nb * (nb - 1.f) * 0.5f / nsb;            // sum t (t<d) / n
        float myb = sy_b / nsb;
        float mxa = na * (na - 1.f) * 0.5f / na;
        float mya = sy_a / na;
        float cov_b = sxy_b - mxb * sy_b;
        float cov_a = sxy_a - mxa * sy_a;
        float var_b = nb * (nb * nb - 1.f) * (1.f / 12.f);
        float var_a = na * (na * na - 1.f) * (1.f / 12.f);
        float slope_b = (var_b > 0.f) ? cov_b / fmaxf(var_b, 1.f) : 0.f;
        float slope_a = (var_a > 0.f) ? cov_a / fmaxf(var_a, 1.f) : 0.f;
        itc_b[c] = fminf(fmaxf(myb - slope_b * mxb, 0.f), 100.f);  // raw slope in intercept
        itc_a[c] = fminf(fmaxf(mya - slope_a * mxa, 0.f), 100.f);
        sc_b[c]  = fminf(fmaxf(slope_b, 0.f), 2.f);
        sc_a[c]  = fminf(fmaxf(slope_a, 0.f), 2.f);
    }

    // pass 2: stream out1, accumulate squared error
    float acc[4] = {0.f,0.f,0.f,0.f};
#pragma unroll
    for (int y = 0; y < YDIM; ++y) {
        float4 v = p1[y * PLANE4];
        float t1[4] = {v.x, v.y, v.z, v.w};
#pragma unroll
        for (int c = 0; c < 4; ++c) {
            float xf  = (float)y;
            float fb  = fmaf(sc_b[c], xf,          itc_b[c]);
            float fa  = fmaf(sc_a[c], xf - fd[c],  itc_a[c]);
            float fit = (xf < fd[c]) ? fb : fa;    // mask_b = t < d
            float e   = fit - t1[c];
            acc[c]    = fmaf(e, e, acc[c]);
        }
    }
    float a = (acc[0] + acc[1]) + (acc[2] + acc[3]);

    // wave (64) reduce, then cross-wave via LDS
#pragma unroll
    for (int off = 32; off > 0; off >>= 1) a += __shfl_down(a, off, 64);
    __shared__ float wsum[NTHR / 64];
    if ((threadIdx.x & 63) == 0) wsum[threadIdx.x >> 6] = a;
    __syncthreads();
    if (threadIdx.x == 0)
        partial[blockIdx.x] = (wsum[0] + wsum[1]) + (wsum[2] + wsum[3]);
}

__global__ __launch_bounds__(NTHR) void drl_reduce(const float* __restrict__ partial,
                                                   float* __restrict__ outp) {
    double s = 0.0;
    for (int i = threadIdx.x; i < NBLK; i += NTHR) s += (double)partial[i];
    __shared__ double sm[NTHR];
    sm[threadIdx.x] = s;
    __syncthreads();
    for (int st = NTHR / 2; st > 0; st >>= 1) {
        if (threadIdx.x < st) sm[threadIdx.x] += sm[threadIdx.x + st];
        __syncthreads();
    }
    if (threadIdx.x == 0) {
        const double N = (double)(8 * YDIM) * 65536.0;  // 15728640 pixels*Y
        outp[0] = (float)(sm[0] / N);
    }
}

extern "C" void kernel_launch(void* const* d_in, const int* in_sizes, int n_in,
                              void* d_out, int out_size, void* d_ws, size_t ws_size,
                              hipStream_t stream) {
    const float4* out_t = (const float4*)d_in[0];  // (8,2,30,256,256) f32
    // d_in[1] = target: unused by the reference loss
    float* partial = (float*)d_ws;                 // NBLK floats
    float* loss    = (float*)d_out;                // scalar f32

    drl_main<<<NBLK, NTHR, 0, stream>>>(out_t, partial);
    drl_reduce<<<1, NTHR, 0, stream>>>(partial, loss);
}